// Round 20
// baseline (50.816 us; speedup 1.0000x reference)
//
#include <hip/hip_runtime.h>

typedef _Float16 f16;
typedef _Float16 f16x8 __attribute__((ext_vector_type(8)));
typedef float f32x4 __attribute__((ext_vector_type(4)));

#define BD 512  // D == H == 512

// async global->LDS, 16B per lane. LDS dest is wave-uniform base + lane*16.
__device__ __forceinline__ void llds16(const void* g, void* l) {
  __builtin_amdgcn_global_load_lds(
      (const __attribute__((address_space(1))) unsigned int*)g,
      (__attribute__((address_space(3))) unsigned int*)l,
      16, 0, 0);
}
__device__ __forceinline__ f16x8 cvt8(float4 a, float4 b) {
  f16x8 h;
  h[0]=(f16)a.x; h[1]=(f16)a.y; h[2]=(f16)a.z; h[3]=(f16)a.w;
  h[4]=(f16)b.x; h[5]=(f16)b.y; h[6]=(f16)b.z; h[7]=(f16)b.w;
  return h;
}

// ---- prep: W fp32->f16 (blocks 0..511) + mem fp32->f16 zero-padded (512..527) ----
__global__ __launch_bounds__(256) void prep_kernel(
    const float* __restrict__ projW, const float* __restrict__ opsW,
    const float* __restrict__ memf, f16* __restrict__ wh,
    f16* __restrict__ memh) {
  const int bid = blockIdx.x, t = threadIdx.x;
  if (bid < 512) {
    const int e = (bid * 256 + t) * 8;
    const float* s = (e < 262144) ? (projW + e) : (opsW + (e - 262144));
    float4 v0 = ((const float4*)s)[0];
    float4 v1 = ((const float4*)s)[1];
    *(f16x8*)&wh[e] = cvt8(v0, v1);
  } else {
    const int e = ((bid - 512) * 256 + t) * 8;   // 16*256*8 = 32768 = 64*512
    const int row = e >> 9;
    f16x8 h;
    if (row < 50) {
      float4 v0 = ((const float4*)(memf + e))[0];
      float4 v1 = ((const float4*)(memf + e))[1];
      h = cvt8(v0, v1);
    } else {
      #pragma unroll
      for (int j = 0; j < 8; ++j) h[j] = (f16)0.f;
    }
    *(f16x8*)&memh[e] = h;
  }
}

// ---- G1+NOV: g0 = relu(x @ projW^T + b). A = x f32 staged DIRECTLY (no xh).
// 64x64 tile, BK=64, ring-2 (32 KB/buf: A16K f32 | B8K | M8K), 2 blocks/CU.
// colPanel==0 blocks also compute novelty partials vs memh (r18/r19-validated).
__global__ __launch_bounds__(256, 2) void gemm1_nov_kernel(
    const float* __restrict__ x, const f16* __restrict__ wh,
    const f16* __restrict__ memh, const float* __restrict__ projB,
    f16* __restrict__ g0, float* __restrict__ novPart) {
  __shared__ __align__(16) char lds[2 * 32768];
  __shared__ float red[4];

  const int t = threadIdx.x, l = t & 63, w = t >> 6;
  const int wr = w >> 1, wc = w & 1;          // wave tile: rows wr*32, cols wc*32
  const int lr = l & 15, lk = l >> 4;
  const int rowBase = blockIdx.x * 64, colBase = blockIdx.y * 64;
  const bool NOV = (blockIdx.y == 0);

  auto stage = [&](int buf, int kt) {
    char* base = lds + buf * 32768;
    #pragma unroll
    for (int i = 0; i < 4; ++i) {             // A: 64r x 64 f32 = 16 KB
      const int o = i * 4096 + t * 16;
      const int row = o >> 8;                 // 256 B per row (64 f32)
      const int sch = ((o >> 4) & 15) ^ (row & 15);   // 16 chunks/row
      llds16(x + (size_t)(rowBase + row) * BD + kt + sch * 4,
             base + i * 4096 + w * 1024);
    }
    #pragma unroll
    for (int i = 0; i < 2; ++i) {             // B: 64r x 64 f16 = 8 KB
      const int o = i * 4096 + t * 16;
      const int row = o >> 7;                 // 128 B per row (64 f16)
      const int sch = ((o >> 4) & 7) ^ (row & 7);
      llds16(wh + (size_t)(colBase + row) * BD + kt + sch * 8,
             base + 16384 + i * 4096 + w * 1024);
    }
    if (NOV) {
      #pragma unroll
      for (int i = 0; i < 2; ++i) {           // M: 64r x 64 f16 = 8 KB
        const int o = i * 4096 + t * 16;
        const int row = o >> 7;
        const int sch = ((o >> 4) & 7) ^ (row & 7);
        llds16(memh + (size_t)row * BD + kt + sch * 8,
               base + 24576 + i * 4096 + w * 1024);
      }
    }
  };

  f32x4 acc[2][2], nacc[4];
  #pragma unroll
  for (int m = 0; m < 2; ++m)
    #pragma unroll
    for (int n = 0; n < 2; ++n) acc[m][n] = (f32x4){0.f,0.f,0.f,0.f};
  #pragma unroll
  for (int q = 0; q < 4; ++q) nacc[q] = (f32x4){0.f,0.f,0.f,0.f};
  float xsq[4] = {0.f, 0.f, 0.f, 0.f};
  float msq = 0.f;

  auto compute = [&](int buf) {
    const float* Ab = (const float*)(lds + buf * 32768);
    const f16* Bb = (const f16*)(lds + buf * 32768 + 16384);
    const f16* Mb = (const f16*)(lds + buf * 32768 + 24576);
    #pragma unroll
    for (int kk = 0; kk < 64; kk += 32) {
      // A fragment: two 16B f32 chunks, each XOR-swizzled independently, cvt->f16
      auto readA = [&](int r) -> f16x8 {
        const int c0 = ((kk >> 2) + 2 * lk) ^ (r & 15);
        const int c1 = ((kk >> 2) + 2 * lk + 1) ^ (r & 15);
        float4 r0 = *(const float4*)&Ab[r * 64 + c0 * 4];
        float4 r1 = *(const float4*)&Ab[r * 64 + c1 * 4];
        return cvt8(r0, r1);
      };
      const int ch = (kk >> 3) + lk;
      f16x8 af[2], bf[2];
      #pragma unroll
      for (int m = 0; m < 2; ++m) af[m] = readA(wr * 32 + m * 16 + lr);
      #pragma unroll
      for (int n = 0; n < 2; ++n) {
        const int row = wc * 32 + n * 16 + lr;
        bf[n] = *(const f16x8*)&Bb[row * 64 + ((ch ^ (row & 7)) << 3)];
      }
      __builtin_amdgcn_s_setprio(1);
      #pragma unroll
      for (int m = 0; m < 2; ++m)
        #pragma unroll
        for (int n = 0; n < 2; ++n)
          acc[m][n] = __builtin_amdgcn_mfma_f32_16x16x32_f16(af[m], bf[n], acc[m][n], 0, 0, 0);
      __builtin_amdgcn_s_setprio(0);
      if (NOV) {
        const int mrow = w * 16 + lr;
        f16x8 mf = *(const f16x8*)&Mb[mrow * 64 + ((ch ^ (mrow & 7)) << 3)];
        #pragma unroll
        for (int j = 0; j < 8; ++j) { float f = (float)mf[j]; msq += f * f; }
        f16x8 aq[4];                          // static indices (rule #20)
        if (wr == 0) {
          aq[0] = af[0]; aq[1] = af[1];
          aq[2] = readA(32 + lr); aq[3] = readA(48 + lr);
        } else {
          aq[0] = readA(lr); aq[1] = readA(16 + lr);
          aq[2] = af[0]; aq[3] = af[1];
        }
        #pragma unroll
        for (int q = 0; q < 4; ++q) {
          #pragma unroll
          for (int j = 0; j < 8; ++j) { float f = (float)aq[q][j]; xsq[q] += f * f; }
          nacc[q] = __builtin_amdgcn_mfma_f32_16x16x32_f16(aq[q], mf, nacc[q], 0, 0, 0);
        }
      }
    }
  };

  // ring-2, ONE barrier/step; stage(t+1) AFTER the barrier (buf (t+1)&1's
  // readers drained at step t-1's lgkmcnt(0), ordered by this barrier).
  stage(0, 0);
  #pragma unroll
  for (int t8 = 0; t8 < 8; ++t8) {
    asm volatile("s_waitcnt vmcnt(0)" ::: "memory");   // my tile-t8 loads landed
    __builtin_amdgcn_s_barrier();
    if (t8 < 7) stage((t8 + 1) & 1, (t8 + 1) * 64);
    compute(t8 & 1);
    asm volatile("s_waitcnt lgkmcnt(0)" ::: "memory"); // my ds_reads drained
  }

  // novelty tail (r18/r19-validated)
  if (NOV) {
    msq += __shfl_xor(msq, 16, 64);
    msq += __shfl_xor(msq, 32, 64);
    #pragma unroll
    for (int q = 0; q < 4; ++q) {
      xsq[q] += __shfl_xor(xsq[q], 16, 64);
      xsq[q] += __shfl_xor(xsq[q], 32, 64);
    }
    const int mm = w * 16 + lr;
    float local = 0.f;
    if (mm < 50) {
      #pragma unroll
      for (int j = 0; j < 4; ++j) {
        const int r16 = lk * 4 + j;            // C/D row-in-16 = (lane>>4)*4 + j
        #pragma unroll
        for (int q = 0; q < 4; ++q) {
          const float xs = __shfl(xsq[q], r16, 64);
          float d = xs - 2.f * nacc[q][j] + msq;
          local += sqrtf(fmaxf(d, 0.f));
        }
      }
    }
    #pragma unroll
    for (int off = 32; off; off >>= 1) local += __shfl_down(local, off, 64);
    if (l == 0) red[w] = local;
    __syncthreads();
    if (t == 0) novPart[blockIdx.x] = red[0] + red[1] + red[2] + red[3];
  }

  // epilogue: bias + relu, store f16
  #pragma unroll
  for (int n = 0; n < 2; ++n) {
    const int col = colBase + wc * 32 + n * 16 + lr;
    const float bbv = projB[col];
    #pragma unroll
    for (int m = 0; m < 2; ++m) {
      #pragma unroll
      for (int j = 0; j < 4; ++j) {
        const int rowg = rowBase + wr * 32 + m * 16 + lk * 4 + j;
        g0[(size_t)rowg * BD + col] = (f16)fmaxf(acc[m][n][j] + bbv, 0.f);
      }
    }
  }
}

// ---- G2/G3: r12-proven ring-4 GEMM (no remap). Wall = wh + 262144 (ops table).
// PICK: 1 = ops_W[idx_a]; 2 = ops_W[idx_b] (block(0,0) finalizes novelty)
template <int PICK, int OUTF16>
__global__ __launch_bounds__(256, 2) void gemm_relu_kernel(
    const f16* __restrict__ A, const f16* __restrict__ Wall,
    const float* __restrict__ ball, const float* __restrict__ logits,
    void* __restrict__ Out, const float* __restrict__ novPart,
    float* __restrict__ novOut) {
  __shared__ __align__(16) char lds[4 * 16384];  // per buf: 8 KB A + 8 KB B

  const int t = threadIdx.x;
  const int l = t & 63;
  const int w = t >> 6;
  const int wr = w >> 1, wc = w & 1;
  const int lr = l & 15, lk = l >> 4;

  if (PICK == 2 && blockIdx.x == 0 && blockIdx.y == 0 && w == 0) {
    float s = novPart[l] + novPart[l + 64];      // 128 partials
    #pragma unroll
    for (int off = 32; off; off >>= 1) s += __shfl_down(s, off, 64);
    if (l == 0) novOut[0] = fminf(1.5f, s * (1.0f / (8192.0f * 50.0f)));
  }

  float l0 = logits[0], l1 = logits[1], l2 = logits[2];
  int ia = 0; float ba = l0;
  if (l1 > ba) { ba = l1; ia = 1; }
  if (l2 > ba) { ba = l2; ia = 2; }
  int widx;
  if (PICK == 1) {
    widx = ia;
  } else {
    int ib = 0; float bb2 = -3.4e38f;
    if (ia != 0)             { bb2 = l0; ib = 0; }
    if (ia != 1 && l1 > bb2) { bb2 = l1; ib = 1; }
    if (ia != 2 && l2 > bb2) { bb2 = l2; ib = 2; }
    widx = ib;
  }
  const f16* W = Wall + (size_t)widx * BD * BD;
  const float* bias = ball + widx * BD;

  const int rowBase = blockIdx.x * 64;
  const int colBase = blockIdx.y * 64;

  f32x4 acc[2][2];
  #pragma unroll
  for (int m = 0; m < 2; ++m)
    #pragma unroll
    for (int n = 0; n < 2; ++n) acc[m][n] = (f32x4){0.f, 0.f, 0.f, 0.f};

  auto stage = [&](int buf, int kt) {
    f16* Ab = (f16*)(lds + buf * 16384);
    f16* Bb = (f16*)(lds + buf * 16384 + 8192);
    #pragma unroll
    for (int i = 0; i < 2; ++i) {
      const int o = i * 4096 + t * 16;
      const int row = o >> 7;                // 128 B per row (64 f16)
      const int sch = ((o >> 4) & 7) ^ (row & 7);
      llds16(A + (size_t)(rowBase + row) * BD + kt + sch * 8,
             (char*)Ab + i * 4096 + w * 1024);
      llds16(W + (size_t)(colBase + row) * BD + kt + sch * 8,
             (char*)Bb + i * 4096 + w * 1024);
    }
  };

  auto compute = [&](int buf) {
    const f16* Ab = (const f16*)(lds + buf * 16384);
    const f16* Bb = (const f16*)(lds + buf * 16384 + 8192);
    #pragma unroll
    for (int kk = 0; kk < 64; kk += 32) {
      const int ch = (kk >> 3) + lk;
      f16x8 af[2], bf[2];
      #pragma unroll
      for (int m = 0; m < 2; ++m) {
        const int row = wr * 32 + m * 16 + lr;
        af[m] = *(const f16x8*)&Ab[row * 64 + ((ch ^ (row & 7)) << 3)];
      }
      #pragma unroll
      for (int n = 0; n < 2; ++n) {
        const int row = wc * 32 + n * 16 + lr;
        bf[n] = *(const f16x8*)&Bb[row * 64 + ((ch ^ (row & 7)) << 3)];
      }
      __builtin_amdgcn_s_setprio(1);
      #pragma unroll
      for (int m = 0; m < 2; ++m)
        #pragma unroll
        for (int n = 0; n < 2; ++n)
          acc[m][n] = __builtin_amdgcn_mfma_f32_16x16x32_f16(af[m], bf[n], acc[m][n], 0, 0, 0);
      __builtin_amdgcn_s_setprio(0);
    }
  };

  stage(0, 0);
  stage(1, 64);
  stage(2, 128);
  #pragma unroll
  for (int t8 = 0; t8 < 8; ++t8) {
    if (t8 < 6)       asm volatile("s_waitcnt vmcnt(8)" ::: "memory");
    else if (t8 == 6) asm volatile("s_waitcnt vmcnt(4)" ::: "memory");
    else              asm volatile("s_waitcnt vmcnt(0)" ::: "memory");
    __builtin_amdgcn_s_barrier();
    if (t8 < 5) stage((t8 + 3) & 3, (t8 + 3) * 64);
    compute(t8 & 3);
    asm volatile("s_waitcnt lgkmcnt(0)" ::: "memory");
  }

  #pragma unroll
  for (int n = 0; n < 2; ++n) {
    const int col = colBase + wc * 32 + n * 16 + lr;
    const float bbv = bias[col];
    #pragma unroll
    for (int m = 0; m < 2; ++m) {
      #pragma unroll
      for (int j = 0; j < 4; ++j) {
        const int rowg = rowBase + wr * 32 + m * 16 + lk * 4 + j;
        float v = fmaxf(acc[m][n][j] + bbv, 0.f);
        if (OUTF16) ((f16*)Out)[(size_t)rowg * BD + col] = (f16)v;
        else        ((float*)Out)[(size_t)rowg * BD + col] = v;
      }
    }
  }
}

extern "C" void kernel_launch(void* const* d_in, const int* in_sizes, int n_in,
                              void* d_out, int out_size, void* d_ws, size_t ws_size,
                              hipStream_t stream) {
  const float* x      = (const float*)d_in[0];   // [8192,512]
  const float* memf   = (const float*)d_in[1];   // [50,512]
  const float* logits = (const float*)d_in[2];   // [3]
  const float* projW  = (const float*)d_in[3];   // [512,512]
  const float* projB  = (const float*)d_in[4];   // [512]
  const float* opsW   = (const float*)d_in[5];   // [3,512,512]
  const float* opsB   = (const float*)d_in[6];   // [3,512]
  float* out = (float*)d_out;                    // [8192*512 + 1]

  char* ws = (char*)d_ws;
  f16*   g0      = (f16*)(ws);                // 8 MB
  f16*   h1      = (f16*)(ws + 8388608);      // 8 MB
  f16*   wh      = (f16*)(ws + 16777216);     // 2 MB: proj_W f16, then ops_W f16
  f16*   memh    = (f16*)(ws + 18874368);     // 64 KB (64x512 zero-padded)
  float* novPart = (float*)(ws + 18939904);   // 512 B (128 floats)

  prep_kernel<<<528, 256, 0, stream>>>(projW, opsW, memf, wh, memh);

  // G1+NOV: g0 = relu(x @ projW^T + projB); x staged f32 directly (no xh pass)
  gemm1_nov_kernel<<<dim3(128, 8), 256, 0, stream>>>(x, wh, memh, projB, g0, novPart);
  // G2: h1 = relu(g0 @ Wa^T + ba)
  gemm_relu_kernel<1, 1><<<dim3(128, 8), 256, 0, stream>>>(
      g0, wh + 262144, opsB, logits, (void*)h1, novPart, out + 4194304);
  // G3: out = relu(h1 @ Wb^T + bb); finalizes novelty scalar
  gemm_relu_kernel<2, 0><<<dim3(128, 8), 256, 0, stream>>>(
      h1, wh + 262144, opsB, logits, (void*)out, novPart, out + 4194304);
}